// Round 1
// 361.611 us; speedup vs baseline: 1.2545x; 1.2545x over previous
//
#include <hip/hip_runtime.h>

// ContinuousAxialDW: out = x + axialH(x) + axialW(x)
// x: [B=8, C=96, H=256, W=256] fp32
//
// R1: per-channel integer stencils prebuilt into d_ws (tiny pre-pass kernel).
// R2 (this round): 4x4 register blocking + XCD-aware swizzle.
//   - Old kernel: 4 outputs/thread, 16 float4 loads each, vertical loads
//     serialized behind per-tap branches -> latency-bound (VALU 28%, HBM 31%).
//   - Now: each thread computes a 4-row x 4-col tile. Loads per 16 outputs:
//     16 neighbor-row center float4 (batched first, uniform-branch gated)
//     + 4 x 5 span float4. ~2.1x less VMEM/output, loads batched for MLP.
//   - Grid = B*C*(H/16); swizzle (bid&7)*1536+(bid>>3) keeps all 16 h-blocks
//     of a plane on one XCD so the 26-row halo footprint is L2-shared
//     (kills the measured 1.73x HBM over-fetch).

constexpr int B = 8, C = 96, H = 256, W = 256;
constexpr int KT = 7;       // taps per axis
constexpr int HALO = 8;     // integer-tap radius (covers r <= ~2.3)
constexpr int NW = 2 * HALO + 1;   // 17
constexpr int RPW = 4;      // output rows per wave (per thread)
constexpr int RPB = 16;     // output rows per block (4 waves)

// d_ws layout: [0 .. C*NW)          = wtv (vertical / H-axis stencil)
//              [C*NW .. 2*C*NW)     = wth (horizontal / W-axis stencil)

__global__ __launch_bounds__(64) void build_stencils(
    const float* __restrict__ wh,
    const float* __restrict__ ww,
    const float* __restrict__ rp,
    float* __restrict__ ws)
{
    const int c = blockIdx.x;        // 0..C-1
    const int d = threadIdx.x;       // 0..63, only d < NW active
    if (d >= NW) return;

    float r = rp[0];
    if (r < 1.0f) r = 1.0f;

    float av = 0.f, aw = 0.f;
#pragma unroll
    for (int i = 0; i < KT; ++i) {
        float s   = (float)(i - 3) * r;   // pixel shift of tap i
        float d0f = floorf(s);
        int   d0  = (int)d0f;
        float f   = s - d0f;              // constant bilinear frac
        float thv = wh[c * KT + i];
        float twv = ww[c * KT + i];
        if (d - HALO == d0)     { av = fmaf(thv, 1.f - f, av); aw = fmaf(twv, 1.f - f, aw); }
        if (d - HALO == d0 + 1) { av = fmaf(thv, f, av);       aw = fmaf(twv, f, aw); }
    }
    ws[c * NW + d]          = av;
    ws[C * NW + c * NW + d] = aw;
}

__global__ __launch_bounds__(256) void axialdw_kernel(
    const float* __restrict__ x,
    const float* __restrict__ ws,
    float* __restrict__ out)
{
    // ---- XCD-aware bijective swizzle: nwg = 12288, divisible by 8 ----
    constexpr int NWG = B * C * (H / RPB);       // 12288
    constexpr int CPX = NWG / 8;                 // 1536
    const int bid = blockIdx.x;
    const int lb  = (bid & 7) * CPX + (bid >> 3);

    const int hb   = lb % (H / RPB);             // h-chunk within plane
    const int bc   = lb / (H / RPB);             // (b,c) plane index
    const int c    = bc % C;
    const int wave = threadIdx.x >> 6;
    const int lane = threadIdx.x & 63;
    const int r0   = hb * RPB + wave * RPW;      // first output row of wave
    const int w0   = lane * 4;

    // block-uniform stencil loads (compiler emits s_load; SGPR-resident)
    float wtv[NW], wth[NW];
#pragma unroll
    for (int d = 0; d < NW; ++d) {
        wtv[d] = ws[c * NW + d];
        wth[d] = ws[C * NW + c * NW + d];
    }

    const float* plane = x + (size_t)bc * (H * W);

    // ---- Phase A: neighbor rows (vertical-only sources), center float4 ----
    // nb[i][.]: i<8 -> row r0-8+i ; i>=8 -> row r0+4+(i-8)   (rel j in [-8,11])
    // Gated by wave-uniform (stencil-window-nonzero && in-bounds) -> s_cbranch,
    // loads stay batched/outstanding across the scalar branches.
    float nbv[16][4];
#pragma unroll
    for (int i = 0; i < 16; ++i) {
        const int j  = (i < 8) ? (i - 8) : (i - 4);   // rel source row
        const int hh = r0 + j;
        bool need = false;
#pragma unroll
        for (int rr = 0; rr < RPW; ++rr) {
            const int d = j - rr + HALO;              // tap feeding (rr <- j)
            if (d >= 0 && d < NW) need = need || (wtv[d] != 0.f);
        }
        float4 v = make_float4(0.f, 0.f, 0.f, 0.f);
        if (need && hh >= 0 && hh < H)
            v = *(const float4*)(plane + (size_t)hh * W + w0);
        nbv[i][0] = v.x; nbv[i][1] = v.y; nbv[i][2] = v.z; nbv[i][3] = v.w;
    }

    // ---- Phase B: per output row: span load + residual + horizontal ----
    float acc[RPW][4];
    float ctr[RPW][4];
#pragma unroll
    for (int rr = 0; rr < RPW; ++rr) {
        const float* row = plane + (size_t)(r0 + rr) * W;

        // span [w0-8, w0+12): 5 float4. Boundary float4s are provably FULLY
        // out-of-range (offsets & W are multiples of 4) -> branchless
        // clamp-address + 0/1 mask, no per-element handling.
        float sp[20];
#pragma unroll
        for (int k = 0; k < 5; ++k) {
            const int wb = w0 - 8 + 4 * k;
            float4 v;
            if (k == 2) {                       // always in-range
                v = *(const float4*)(row + wb);
            } else {
                const bool ok = ((unsigned)wb < (unsigned)W);
                v = *(const float4*)(row + (ok ? wb : 0));
                const float m = ok ? 1.f : 0.f;
                v.x *= m; v.y *= m; v.z *= m; v.w *= m;
            }
            sp[4 * k + 0] = v.x; sp[4 * k + 1] = v.y;
            sp[4 * k + 2] = v.z; sp[4 * k + 3] = v.w;
        }

#pragma unroll
        for (int e = 0; e < 4; ++e) {
            ctr[rr][e] = sp[HALO + e];          // center, reused in Phase C
            acc[rr][e] = sp[HALO + e];          // residual x
        }
#pragma unroll
        for (int d = 0; d < NW; ++d) {
            const float wg = wth[d];
#pragma unroll
            for (int e = 0; e < 4; ++e)
                acc[rr][e] = fmaf(wg, sp[d + e], acc[rr][e]);
        }
    }

    // ---- Phase C: vertical stencil from register file ----
#pragma unroll
    for (int rr = 0; rr < RPW; ++rr) {
#pragma unroll
        for (int d = 0; d < NW; ++d) {
            const float wg = wtv[d];
            const int j = rr + d - HALO;        // rel source row in [-8, 11]
#pragma unroll
            for (int e = 0; e < 4; ++e) {
                float s;
                if (j >= 0 && j <= 3)      s = ctr[j][e];
                else if (j < 0)            s = nbv[j + 8][e];
                else                       s = nbv[j + 4][e];
                acc[rr][e] = fmaf(wg, s, acc[rr][e]);
            }
        }
    }

    // ---- store: 4 coalesced float4 rows ----
    float* obase = out + (size_t)bc * (H * W);
#pragma unroll
    for (int rr = 0; rr < RPW; ++rr) {
        float4 o;
        o.x = acc[rr][0]; o.y = acc[rr][1]; o.z = acc[rr][2]; o.w = acc[rr][3];
        *(float4*)(obase + (size_t)(r0 + rr) * W + w0) = o;
    }
}

extern "C" void kernel_launch(void* const* d_in, const int* in_sizes, int n_in,
                              void* d_out, int out_size, void* d_ws, size_t ws_size,
                              hipStream_t stream) {
    const float* x  = (const float*)d_in[0];
    const float* wh = (const float*)d_in[1];
    const float* ww = (const float*)d_in[2];
    const float* rp = (const float*)d_in[3];
    float* out = (float*)d_out;
    float* ws  = (float*)d_ws;

    build_stencils<<<C, 64, 0, stream>>>(wh, ww, rp, ws);
    const int blocks = B * C * (H / RPB);   // 12288
    axialdw_kernel<<<blocks, 256, 0, stream>>>(x, ws, out);
}

// Round 2
// 339.472 us; speedup vs baseline: 1.3363x; 1.0652x over previous
//
#include <hip/hip_runtime.h>

// ContinuousAxialDW: out = x + axialH(x) + axialW(x)
// x: [B=8, C=96, H=256, W=256] fp32
//
// R1: per-channel integer stencils prebuilt into d_ws (tiny pre-pass kernel).
// R2: 4x4 register blocking + XCD swizzle. FETCH 340->98 MB, 224->129 us, but
//     VGPR=64 shows the compiler serialized the "batched" loads -> latency-bound.
// R3 (this round): cooperative LDS staging.
//   - WG (256 thr) stages its 32-row x 256-col source tile into LDS with
//     8 global_load_lds_dwordx4 per wave (coalesced, dependency-free, no VGPR
//     round-trip), halo cols pre-zeroed -> inner loops are maskless.
//   - Compute reads LDS (contiguous 16B/lane pattern = conflict-free).
//   - Budget: HBM ~47-64 us >> LDS ~29 us, VALU ~20 us -> memory-bound.

constexpr int B = 8, C = 96, H = 256, W = 256;
constexpr int KT = 7;              // taps per axis
constexpr int HALO = 8;            // integer-tap radius (covers r <= ~2.3)
constexpr int NW = 2 * HALO + 1;   // 17
constexpr int RPB = 16;            // output rows per block (4 waves x 4 rows)
constexpr int SR = RPB + 2 * HALO; // 32 staged rows
constexpr int LDW = W + 16;        // 272: 8-col zero halo each side

// d_ws layout: [0 .. C*NW)          = wtv (vertical / H-axis stencil)
//              [C*NW .. 2*C*NW)     = wth (horizontal / W-axis stencil)

__global__ __launch_bounds__(64) void build_stencils(
    const float* __restrict__ wh,
    const float* __restrict__ ww,
    const float* __restrict__ rp,
    float* __restrict__ ws)
{
    const int c = blockIdx.x;        // 0..C-1
    const int d = threadIdx.x;       // 0..63, only d < NW active
    if (d >= NW) return;

    float r = rp[0];
    if (r < 1.0f) r = 1.0f;

    float av = 0.f, aw = 0.f;
#pragma unroll
    for (int i = 0; i < KT; ++i) {
        float s   = (float)(i - 3) * r;   // pixel shift of tap i
        float d0f = floorf(s);
        int   d0  = (int)d0f;
        float f   = s - d0f;              // constant bilinear frac
        float thv = wh[c * KT + i];
        float twv = ww[c * KT + i];
        if (d - HALO == d0)     { av = fmaf(thv, 1.f - f, av); aw = fmaf(twv, 1.f - f, aw); }
        if (d - HALO == d0 + 1) { av = fmaf(thv, f, av);       aw = fmaf(twv, f, aw); }
    }
    ws[c * NW + d]          = av;
    ws[C * NW + c * NW + d] = aw;
}

__global__ __launch_bounds__(256, 4) void axialdw_kernel(
    const float* __restrict__ x,
    const float* __restrict__ ws,
    float* __restrict__ out)
{
    __shared__ float tile[SR][LDW];      // 32 x 272 floats = 34,816 B

    // ---- XCD-aware bijective swizzle (nwg = 12288, divisible by 8) ----
    constexpr int NWG = B * C * (H / RPB);       // 12288
    constexpr int CPX = NWG / 8;                 // 1536
    const int bid = blockIdx.x;
    const int lb  = (bid & 7) * CPX + (bid >> 3);

    const int hb   = lb % (H / RPB);             // h-chunk within plane
    const int bc   = lb / (H / RPB);             // (b,c) plane index
    const int c    = bc % C;
    const int tid  = threadIdx.x;
    const int wave = tid >> 6;
    const int lane = tid & 63;
    const int w0   = lane * 4;

    const float* plane = x + (size_t)bc * (H * W);
    const int gr0 = hb * RPB - HALO;             // global row of LDS row 0

    // ---- stage: wave w loads LDS rows w, w+4, ..., w+28 (1 KB each) ----
#pragma unroll
    for (int it = 0; it < SR / 4; ++it) {
        const int i  = wave + 4 * it;            // LDS row (wave-uniform)
        const int gr = gr0 + i;                  // global row
        if (gr >= 0 && gr < H) {
            const float* gsrc = plane + (size_t)gr * W + w0;   // per-lane
            __builtin_amdgcn_global_load_lds(
                (const __attribute__((address_space(1))) void*)gsrc,
                (__attribute__((address_space(3))) void*)&tile[i][HALO],  // uniform base; HW adds lane*16
                16, 0, 0);
        } else {
            *(float4*)&tile[i][HALO + w0] = make_float4(0.f, 0.f, 0.f, 0.f);
        }
    }

    // ---- zero the 8-col horizontal halos (128 threads x one float4) ----
    if (tid < SR * 4) {
        const int i = tid >> 2;
        const int q = tid & 3;
        const int col = (q < 2) ? q * 4 : (W + (q - 2) * 4 + 8);  // 0,4,264,268
        *(float4*)&tile[i][col] = make_float4(0.f, 0.f, 0.f, 0.f);
    }

    // block-uniform stencil loads (uniform c -> s_load)
    float wtv[NW], wth[NW];
#pragma unroll
    for (int d = 0; d < NW; ++d) {
        wtv[d] = ws[c * NW + d];
        wth[d] = ws[C * NW + c * NW + d];
    }

    __syncthreads();   // drains vmcnt (global_load_lds) + lgkmcnt (ds_write)

    const int rbase = wave * 4;      // first output row, relative to hb*RPB

    // ---- per output row: span from LDS + residual + horizontal ----
    float acc[4][4];
    float ctr[4][4];
#pragma unroll
    for (int rr = 0; rr < 4; ++rr) {
        // output row's LDS row = rbase + rr + 8; span cols w0 .. w0+19
        const float* lrow = &tile[rbase + 8 + rr][w0];
        float sp[20];
#pragma unroll
        for (int k = 0; k < 5; ++k) {
            const float4 v = *(const float4*)(lrow + 4 * k);
            sp[4 * k + 0] = v.x; sp[4 * k + 1] = v.y;
            sp[4 * k + 2] = v.z; sp[4 * k + 3] = v.w;
        }
#pragma unroll
        for (int e = 0; e < 4; ++e) {
            ctr[rr][e] = sp[HALO + e];      // x itself (reused by vertical)
            acc[rr][e] = sp[HALO + e];      // residual
        }
#pragma unroll
        for (int d = 0; d < NW; ++d) {
            const float wg = wth[d];
            if (wg != 0.f) {                 // uniform zero-tap skip
#pragma unroll
                for (int e = 0; e < 4; ++e)
                    acc[rr][e] = fmaf(wg, sp[d + e], acc[rr][e]);
            }
        }
    }

    // ---- vertical: source LDS row = rbase + s, s = rr + d in [0,19] ----
#pragma unroll
    for (int s = 0; s < 20; ++s) {
        float v[4];
        if (s >= 8 && s <= 11) {
            // center rows already in registers
#pragma unroll
            for (int e = 0; e < 4; ++e) v[e] = ctr[s - 8][e];
        } else {
            bool need = false;
#pragma unroll
            for (int rr = 0; rr < 4; ++rr) {
                const int d = s - rr;
                if (d >= 0 && d < NW) need = need || (wtv[d] != 0.f);
            }
            if (!need) continue;             // uniform skip: row feeds nothing
            const float4 t = *(const float4*)&tile[rbase + s][HALO + w0];
            v[0] = t.x; v[1] = t.y; v[2] = t.z; v[3] = t.w;
        }
#pragma unroll
        for (int rr = 0; rr < 4; ++rr) {
            const int d = s - rr;
            if (d >= 0 && d < NW) {
                const float wg = wtv[d];
#pragma unroll
                for (int e = 0; e < 4; ++e)
                    acc[rr][e] = fmaf(wg, v[e], acc[rr][e]);
            }
        }
    }

    // ---- store: 4 coalesced float4 rows ----
    float* obase = out + (size_t)bc * (H * W)
                 + (size_t)(hb * RPB + rbase) * W + w0;
#pragma unroll
    for (int rr = 0; rr < 4; ++rr) {
        float4 o;
        o.x = acc[rr][0]; o.y = acc[rr][1]; o.z = acc[rr][2]; o.w = acc[rr][3];
        *(float4*)(obase + (size_t)rr * W) = o;
    }
}

extern "C" void kernel_launch(void* const* d_in, const int* in_sizes, int n_in,
                              void* d_out, int out_size, void* d_ws, size_t ws_size,
                              hipStream_t stream) {
    const float* x  = (const float*)d_in[0];
    const float* wh = (const float*)d_in[1];
    const float* ww = (const float*)d_in[2];
    const float* rp = (const float*)d_in[3];
    float* out = (float*)d_out;
    float* ws  = (float*)d_ws;

    build_stencils<<<C, 64, 0, stream>>>(wh, ww, rp, ws);
    const int blocks = B * C * (H / RPB);   // 12288
    axialdw_kernel<<<blocks, 256, 0, stream>>>(x, ws, out);
}